// Round 9
// baseline (174.516 us; speedup 1.0000x reference)
//
#include <hip/hip_runtime.h>

#define N_NODES 8192
#define N_EDGES 65536
#define FEAT    136
#define WNUM    3392

typedef __attribute__((ext_vector_type(4))) short s16x4;
typedef __attribute__((ext_vector_type(8))) short s16x8;
typedef __attribute__((ext_vector_type(4))) float f32x4;
typedef __attribute__((ext_vector_type(2))) float f32x2;

__device__ __forceinline__ float b2f(unsigned short h) {
    union { unsigned int u; float f; } v; v.u = ((unsigned int)h) << 16; return v.f;
}
__device__ __forceinline__ unsigned short f2b(float f) {
    union { float f; unsigned int u; } v; v.f = f;
    unsigned int u = v.u;
    unsigned int r = (u + 0x7FFFu + ((u >> 16) & 1u)) >> 16;
    return (unsigned short)r;
}

// total scale for W2 column `col` = 1/sqrt(fan_in) * per-i sub-factor (inv_s3/inv_s2)
__device__ __forceinline__ float wscale(int col) {
    const float inv_s3 = 0.57735026918962576f;
    const float inv_s2 = 0.70710678118654752f;
    if (col < 1536) { int i = col >> 5;          return 0.14433756729740643f * (i < 32 ? 1.f : inv_s3); }
    if (col < 2560) { int i = (col - 1536) >> 4; return 0.125f               * (i >= 48 ? inv_s2 : 1.f); }
    if (col < 3200) { int i = (col - 2560) >> 4; return 0.15811388300841897f * (i < 16 ? inv_s2 : 1.f); }
    {               int i = (col - 3200) >> 3;   return 0.20412414523193150f * (i < 16 ? inv_s3 : 1.f); }
}

// ---- prep: W2 -> w2t in 16x16-MFMA fragment order; W1 -> w1t; b2 -> b2s; blocks >=54 zero acc/cnt ----
// w2t layout (shorts): [chunk c (64 cols)][t 0..3][half 0..1][lane 0..63][j 0..7]
//   element = W2scaled[k = half*32 + (lane>>4)*8 + j][col = c*64 + t*16 + (lane&15)]
__global__ void transpose_kernel(const float* __restrict__ w2,
                                 const float* __restrict__ w1,
                                 const float* __restrict__ bias2,
                                 unsigned short* __restrict__ w2t,
                                 unsigned short* __restrict__ w1t,
                                 float* __restrict__ b2s,
                                 float* __restrict__ zero_base) {
    __shared__ float tl[64 * 65];
    const int b = blockIdx.x, tid = threadIdx.x;
    if (b >= 54) {
        // zero acc_g + cnt_g: 4489216 bytes = 280576 float4
        int idx = (b - 54) * 256 + tid;
        float4 z = {0.f, 0.f, 0.f, 0.f};
        if (idx < 280576) ((float4*)zero_base)[idx] = z;
        return;
    }
    if (b < 53) {
        const int c0 = b * 64;
        for (int idx = tid; idx < 4096; idx += 256) {
            int k = idx >> 6, c = idx & 63;
            tl[c * 65 + k] = w2[k * WNUM + c0 + c];          // coalesced read over c
        }
        __syncthreads();
        for (int idx = tid; idx < 4096; idx += 256) {
            int fl   = idx >> 10;            // t
            int rem  = idx & 1023;
            int half = rem >> 9;
            int ln   = (rem >> 3) & 63;
            int j    = idx & 7;
            int q = ln >> 4, nn = ln & 15;
            int cl  = fl * 16 + nn;
            int k   = half * 32 + q * 8 + j;
            int col = c0 + cl;
            w2t[(size_t)b * 4096 + idx] = f2b(tl[cl * 65 + k] * wscale(col));
        }
        if (tid < 64) {
            int col = c0 + tid;
            b2s[col] = bias2[col] * wscale(col);
        }
    } else {
        for (int idx = tid; idx < 4096; idx += 256) {
            int k = idx >> 6, j = idx & 63;
            tl[j * 65 + k] = w1[k * 64 + j];
        }
        __syncthreads();
        for (int idx = tid; idx < 4096; idx += 256) {
            int j = idx >> 6, k = idx & 63;
            w1t[j * 64 + k] = f2b(tl[j * 65 + k]);
        }
    }
}

// async 16B/lane global -> LDS copy; LDS dest is wave-uniform base + lane*16
__device__ __forceinline__ void gload_lds16(const unsigned short* g, unsigned short* l) {
    __builtin_amdgcn_global_load_lds(
        (const __attribute__((address_space(1))) unsigned int*)g,
        (__attribute__((address_space(3))) unsigned int*)l, 16, 0, 0);
}

// ---------------- fused main kernel: 64 edges per block, 8 waves (512 thr) ----------------
// Wave role split: wave = (et = wv&3: 16-edge tile, ch = wv>>2: col-half). Each wave covers
// its 16 edges x 2 col-tiles (t in {2ch, 2ch+1}): 4 ds_read_b128 + 4 MFMA + half the o-factor
// VALU per chunk -> per-wave chunk body (the barrier-lockstep critical path) HALVES while
// per-lane Y state stays 36 f32 (no r3-style register cliff). The two ch waves hold partial
// sums over i; epilogue does two-pass EMIT (= then +=).
// (512,4): cap 128 VGPR, 2 blocks/CU (16 waves); <=64 VGPR would give 32 waves (100%).
__global__ __launch_bounds__(512, 4)
void tpconv_main(const float* __restrict__ node_attr,
                 const int* __restrict__ edge_index,
                 const float* __restrict__ edge_attr,
                 const float* __restrict__ edge_sh,
                 const unsigned short* __restrict__ w1t,
                 const float* __restrict__ b1,
                 const unsigned short* __restrict__ w2t,
                 const float* __restrict__ b2s,
                 float* __restrict__ acc_g,
                 float* __restrict__ cnt_g) {
    // LDS layout (37632 B):
    //  [0, 18944)      x gather, bf16, 64 rows x stride 148          (live through K-loop)
    //  [18944, 35328)  W2 chunk double-buffer, 2 x 8192 B, fragment-linear
    //     overlays (dead before staging starts):
    //     [18944, 28160)  h tile, bf16, 64 x 72
    //     [28160, 29184)  sh, f32, 64 x 4
    //     [29184, 29440)  dst (int 64)
    //  [37120, 37376)  src (int 64)  -- survives epilogue stage reuse
    //  epilogue: [0, 37120) reused as f32 Y staging, 64 rows x stride 145
    __shared__ __align__(16) char smem[37632];
    unsigned short* x_lds = (unsigned short*)smem;
    unsigned short* wbuf  = (unsigned short*)(smem + 18944);
    unsigned short* h_lds = (unsigned short*)(smem + 18944);
    float* sh_lds = (float*)(smem + 28160);
    int* dst_lds  = (int*)(smem + 29184);
    int* src_lds  = (int*)(smem + 37120);

    const int tid  = threadIdx.x;
    const int lane = tid & 63;
    const int wv   = tid >> 6;       // wave 0..7
    const int n    = lane & 15;
    const int quad = lane >> 4;
    const int et   = wv & 3;         // 16-edge tile
    const int ch   = wv >> 2;        // col-half: t in {2ch, 2ch+1}
    const int eb   = blockIdx.x * 64;

    // ---- phase A: indices, sh, counts + h = relu(ea @ W1 + b1) -> h_lds ----
    if (tid < 64) {
        int s = edge_index[eb + tid];
        int d = edge_index[N_EDGES + eb + tid];
        src_lds[tid] = s;
        dst_lds[tid] = d;
        atomicAdd(&cnt_g[s], 1.0f);
        const float4 shv = *(const float4*)&edge_sh[(size_t)(eb + tid) * 4];
        sh_lds[tid * 4 + 0] = shv.x;
        sh_lds[tid * 4 + 1] = shv.y;
        sh_lds[tid * 4 + 2] = shv.z;
        sh_lds[tid * 4 + 3] = shv.w;
    }
    {
        // wave (et, ch) computes h cols ct in {2ch, 2ch+1} for its 16 edges
        const float* ea = edge_attr + (size_t)(eb + et * 16 + n) * 64 + quad * 8;
        s16x8 a0, a1;
#pragma unroll
        for (int j = 0; j < 8; ++j) {
            a0[j] = (short)f2b(ea[j]);        // A[m=n][k=quad*8+j]
            a1[j] = (short)f2b(ea[32 + j]);
        }
#pragma unroll
        for (int c2 = 0; c2 < 2; ++c2) {
            int col = (2 * ch + c2) * 16 + n;
            const unsigned short* wp = w1t + col * 64;
            s16x8 bu0 = *(const s16x8*)&wp[quad * 8];
            s16x8 bu1 = *(const s16x8*)&wp[32 + quad * 8];
            f32x4 acc = {0.f, 0.f, 0.f, 0.f};
            acc = __builtin_amdgcn_mfma_f32_16x16x32_bf16(a0, bu0, acc, 0, 0, 0);
            acc = __builtin_amdgcn_mfma_f32_16x16x32_bf16(a1, bu1, acc, 0, 0, 0);
            float bias = b1[col];
            for (int r = 0; r < 4; ++r) {
                float hv = acc[r] + bias;
                hv = hv > 0.f ? hv : 0.f;
                h_lds[(et * 16 + quad * 4 + r) * 72 + col] = f2b(hv);
            }
        }
    }
    __syncthreads();   // h, dst, sh visible

    // ---- phase B: x gather (node_attr[dst] -> bf16) + pull h/sh into regs ----
    for (int idx = tid; idx < 64 * 34; idx += 512) {
        int e = idx / 34, seg = idx - e * 34;
        const float4 v = *(const float4*)(node_attr + (size_t)dst_lds[e] * FEAT + seg * 4);
        s16x4 pk;
        pk[0] = (short)f2b(v.x); pk[1] = (short)f2b(v.y);
        pk[2] = (short)f2b(v.z); pk[3] = (short)f2b(v.w);
        *(s16x4*)&x_lds[e * 148 + seg * 4] = pk;
    }
    const int eLoc = et * 16 + n;
    const float sh0 = sh_lds[eLoc * 4 + 0];
    const float s1x = sh_lds[eLoc * 4 + 1];
    const float s1y = sh_lds[eLoc * 4 + 2];
    const float s1z = sh_lds[eLoc * 4 + 3];
    const unsigned short* hp = &h_lds[eLoc * 72];
    s16x8 h0 = *(const s16x8*)&hp[quad * 8];          // B[k=quad*8+j][n=edge]
    s16x8 h1 = *(const s16x8*)&hp[32 + quad * 8];
    const unsigned short* xr = &x_lds[eLoc * 148];

    __syncthreads();   // x visible; h/sh/dst now dead -> wbuf may overwrite

    // prologue: stage chunk 0 (each wave stages its 1KB slice) + load bias(0) for this col-half
    {
        const unsigned short* g = w2t + (wv << 9) + (lane << 3);
        gload_lds16(g, wbuf + (wv << 9));
    }
    f32x4 bvv[2];                       // bias for the CURRENT chunk's 2 col-tiles
#pragma unroll
    for (int b = 0; b < 2; ++b)
        bvv[b] = *(const f32x4*)(b2s + (2 * ch + b) * 16 + quad * 4);

    f32x2 Y0e2[2][2] = {};   // [row-pair][b = out-block]
    f32x2 Y1o2[2][3] = {};   // [row-pair][comp]  (partial over this wave's i's)
    f32x2 Y1e2[2][3] = {};
    f32x2 Y0o2[2]    = {};

    // Per-chunk top: barrier (drains stage(c) + bvv(c)), issue stage c+1 (1KB/wave),
    // set chunk base for this wave's col-half, batch-load its 4 A-fragments.
#define CHUNK_TOP(c)                                                          \
    __syncthreads();                                                          \
    if ((c) < 52) {                                                           \
        const unsigned short* g = w2t + (((size_t)(c) + 1) << 12) + (wv << 9) + (lane << 3); \
        gload_lds16(g, wbuf + ((((c) + 1) & 1) << 12) + (wv << 9));           \
    }                                                                         \
    const unsigned short* cb = wbuf + (((c) & 1) << 12) + (ch << 11) + (lane << 3); \
    s16x8 Afr[4];                                                             \
    Afr[0] = *(const s16x8*)(cb);                                             \
    Afr[1] = *(const s16x8*)(cb + 512);                                       \
    Afr[2] = *(const s16x8*)(cb + 1024);                                      \
    Afr[3] = *(const s16x8*)(cb + 1536);

    // Body end: refill bvv for chunk c+1 (drained by the next barrier alongside the stage).
#define CHUNK_REFILL(c)                                                       \
    if ((c) < 52) {                                                           \
        _Pragma("unroll")                                                     \
        for (int b = 0; b < 2; ++b)                                           \
            bvv[b] = *(const f32x4*)(b2s + ((c) + 1) * 64 + (2 * ch + b) * 16 + quad * 4); \
    }

#define MFMA_T(b)                                                             \
    f32x4 acc = bvv[b];                                                       \
    acc = __builtin_amdgcn_mfma_f32_16x16x32_bf16(Afr[2 * (b)], h0, acc, 0, 0, 0);     \
    acc = __builtin_amdgcn_mfma_f32_16x16x32_bf16(Afr[2 * (b) + 1], h1, acc, 0, 0, 0); \
    f32x2 a01 = {acc[0], acc[1]}; f32x2 a23 = {acc[2], acc[3]};

#define ACC3(Y)                                                               \
    Y[0][0] += a01 * o0; Y[1][0] += a23 * o0;                                 \
    Y[0][1] += a01 * o1; Y[1][1] += a23 * o1;                                 \
    Y[0][2] += a01 * o2; Y[1][2] += a23 * o2;

    // ---- 0e, i < 32 (i = 2c + ch, wave-const per chunk): x0e[i]*sh0 ----
    for (int c = 0; c < 16; ++c) {
        CHUNK_TOP(c)
        const float ov = b2f(xr[2 * c + ch]) * sh0;
#pragma unroll
        for (int b = 0; b < 2; ++b) {
            MFMA_T(b)
            Y0e2[0][b] += a01 * ov;
            Y0e2[1][b] += a23 * ov;
        }
        CHUNK_REFILL(c)
    }
    // ---- 0e, 32 <= i < 48: dot(x1o[i-32], sh1) ----
    for (int c = 16; c < 24; ++c) {
        CHUNK_TOP(c)
        int ib = 32 + 3 * (2 * c + ch - 32);
        const float ov = b2f(xr[ib]) * s1x + b2f(xr[ib + 1]) * s1y + b2f(xr[ib + 2]) * s1z;
#pragma unroll
        for (int b = 0; b < 2; ++b) {
            MFMA_T(b)
            Y0e2[0][b] += a01 * ov;
            Y0e2[1][b] += a23 * ov;
        }
        CHUNK_REFILL(c)
    }
    // ---- 1o, i < 32 (i = 4(c-24) + 2ch + b): x0e[i]*sh1 ----
    for (int c = 24; c < 32; ++c) {
        CHUNK_TOP(c)
#pragma unroll
        for (int b = 0; b < 2; ++b) {
            MFMA_T(b)
            float xv = b2f(xr[4 * (c - 24) + 2 * ch + b]);
            float o0 = xv * s1x, o1 = xv * s1y, o2 = xv * s1z;
            ACC3(Y1o2)
        }
        CHUNK_REFILL(c)
    }
    // ---- 1o, 32 <= i < 48: x1o[i-32]*sh0 ----
    for (int c = 32; c < 36; ++c) {
        CHUNK_TOP(c)
#pragma unroll
        for (int b = 0; b < 2; ++b) {
            MFMA_T(b)
            int ib = 32 + 3 * (4 * (c - 24) + 2 * ch + b - 32);
            float o0 = b2f(xr[ib]) * sh0, o1 = b2f(xr[ib + 1]) * sh0, o2 = b2f(xr[ib + 2]) * sh0;
            ACC3(Y1o2)
        }
        CHUNK_REFILL(c)
    }
    // ---- 1o, i >= 48: cross(x1e[i-48], sh1) ----
    for (int c = 36; c < 40; ++c) {
        CHUNK_TOP(c)
#pragma unroll
        for (int b = 0; b < 2; ++b) {
            MFMA_T(b)
            int ib = 80 + 3 * (4 * (c - 24) + 2 * ch + b - 48);
            float a0v = b2f(xr[ib]), a1v = b2f(xr[ib + 1]), a2v = b2f(xr[ib + 2]);
            float o0 = a1v * s1z - a2v * s1y;
            float o1 = a2v * s1x - a0v * s1z;
            float o2 = a0v * s1y - a1v * s1x;
            ACC3(Y1o2)
        }
        CHUNK_REFILL(c)
    }
    // ---- 1e, i < 16 (i = 4(c-40) + 2ch + b): cross(x1o[i], sh1) ----
    for (int c = 40; c < 44; ++c) {
        CHUNK_TOP(c)
#pragma unroll
        for (int b = 0; b < 2; ++b) {
            MFMA_T(b)
            int ib = 32 + 3 * (4 * (c - 40) + 2 * ch + b);
            float a0v = b2f(xr[ib]), a1v = b2f(xr[ib + 1]), a2v = b2f(xr[ib + 2]);
            float o0 = a1v * s1z - a2v * s1y;
            float o1 = a2v * s1x - a0v * s1z;
            float o2 = a0v * s1y - a1v * s1x;
            ACC3(Y1e2)
        }
        CHUNK_REFILL(c)
    }
    // ---- 1e, 16 <= i < 32: x1e[i-16]*sh0 ----
    for (int c = 44; c < 48; ++c) {
        CHUNK_TOP(c)
#pragma unroll
        for (int b = 0; b < 2; ++b) {
            MFMA_T(b)
            int ib = 80 + 3 * (4 * (c - 40) + 2 * ch + b - 16);
            float o0 = b2f(xr[ib]) * sh0, o1 = b2f(xr[ib + 1]) * sh0, o2 = b2f(xr[ib + 2]) * sh0;
            ACC3(Y1e2)
        }
        CHUNK_REFILL(c)
    }
    // ---- 1e, i >= 32: x0o[i-32]*sh1 ----
    for (int c = 48; c < 50; ++c) {
        CHUNK_TOP(c)
#pragma unroll
        for (int b = 0; b < 2; ++b) {
            MFMA_T(b)
            float xv = b2f(xr[128 + (4 * (c - 40) + 2 * ch + b - 32)]);
            float o0 = xv * s1x, o1 = xv * s1y, o2 = xv * s1z;
            ACC3(Y1e2)
        }
        CHUNK_REFILL(c)
    }
    // ---- 0o, i < 16 (i = 8(c-50) + 4ch + 2b + (quad>>1)): dot(x1e[i], sh1) ----
    for (int c = 50; c < 52; ++c) {
        CHUNK_TOP(c)
#pragma unroll
        for (int b = 0; b < 2; ++b) {
            MFMA_T(b)
            int ib = 80 + 3 * (8 * (c - 50) + 4 * ch + 2 * b + (quad >> 1));
            float ov = b2f(xr[ib]) * s1x + b2f(xr[ib + 1]) * s1y + b2f(xr[ib + 2]) * s1z;
            Y0o2[0] += a01 * ov;
            Y0o2[1] += a23 * ov;
        }
        CHUNK_REFILL(c)
    }
    // ---- 0o, i >= 16: x0o[i-16]*sh0 ----
    {
        CHUNK_TOP(52)
#pragma unroll
        for (int b = 0; b < 2; ++b) {
            MFMA_T(b)
            float ov = b2f(xr[128 + 4 * ch + 2 * b + (quad >> 1)]) * sh0;
            Y0o2[0] += a01 * ov;
            Y0o2[1] += a23 * ov;
        }
    }
#undef ACC3
#undef MFMA_T
#undef CHUNK_TOP
#undef CHUNK_REFILL

    // ---- stage Y rows in LDS: ch=0 waves write, ch=1 waves add (partials over i), then scatter ----
    __syncthreads();                          // everyone done reading x / wbuf
    float* stage = (float*)smem;              // 64 rows x 145 f32
    float* srow = stage + eLoc * 145;

#define EMIT(OPEQ)                                                            \
    _Pragma("unroll")                                                         \
    for (int r = 0; r < 4; ++r) {                                             \
        const int p = r >> 1, s = r & 1;                                      \
        int qr = quad * 4 + r;                                                \
        srow[qr]              OPEQ Y0e2[p][0][s];                             \
        srow[16 + qr]         OPEQ Y0e2[p][1][s];                             \
        srow[32 + qr * 3 + 0] OPEQ Y1o2[p][0][s];                             \
        srow[32 + qr * 3 + 1] OPEQ Y1o2[p][1][s];                             \
        srow[32 + qr * 3 + 2] OPEQ Y1o2[p][2][s];                             \
        srow[80 + qr * 3 + 0] OPEQ Y1e2[p][0][s];                             \
        srow[80 + qr * 3 + 1] OPEQ Y1e2[p][1][s];                             \
        srow[80 + qr * 3 + 2] OPEQ Y1e2[p][2][s];                             \
        srow[128 + (quad & 1) * 4 + r + (quad >> 1) * 8] OPEQ Y0o2[p][s];     \
    }

    if (ch == 0) { EMIT(=) }
    __syncthreads();
    if (ch == 1) { EMIT(+=) }
#undef EMIT
    __syncthreads();

    // wave wv scatters 8 edges, lanes cover consecutive features (coalesced)
    for (int j = 0; j < 8; ++j) {
        int e = wv * 8 + j;
        float* dp = acc_g + (size_t)src_lds[e] * FEAT;
        const float* sr = stage + e * 145;
        atomicAdd(dp + lane,      sr[lane]);
        atomicAdd(dp + 64 + lane, sr[64 + lane]);
        if (lane < 8)
            atomicAdd(dp + 128 + lane, sr[128 + lane] + sr[136 + lane]);
    }
}

// ---------------- finalize: mean + residual (fp32 out) ----------------
__global__ void finalize_kernel(const float* __restrict__ acc_g,
                                const float* __restrict__ cnt_g,
                                const float* __restrict__ node_attr,
                                float* __restrict__ out) {
    int idx = blockIdx.x * 256 + threadIdx.x;
    if (idx >= N_NODES * FEAT) return;
    int nn = idx / FEAT;
    float c = cnt_g[nn];
    out[idx] = acc_g[idx] / fmaxf(c, 1.0f) + node_attr[idx];
}

extern "C" void kernel_launch(void* const* d_in, const int* in_sizes, int n_in,
                              void* d_out, int out_size, void* d_ws, size_t ws_size,
                              hipStream_t stream) {
    const float* node_attr  = (const float*)d_in[0];
    const int*   edge_index = (const int*)d_in[1];
    const float* edge_attr  = (const float*)d_in[2];
    const float* edge_sh    = (const float*)d_in[3];
    const float* fc_w1      = (const float*)d_in[4];
    const float* fc_b1      = (const float*)d_in[5];
    const float* fc_w2      = (const float*)d_in[6];
    const float* fc_b2      = (const float*)d_in[7];
    float* out = (float*)d_out;

    char* ws = (char*)d_ws;
    float* acc_g = (float*)ws;                                      // 8192*136*4 = 4456448
    float* cnt_g = (float*)(ws + 4456448);                          // 32768
    unsigned short* w2t = (unsigned short*)(ws + 4489216);          // 434176
    unsigned short* w1t = (unsigned short*)(ws + 4489216 + 434176); // 8192
    float* b2s = (float*)(ws + 4489216 + 434176 + 8192);            // 13568

    // blocks 0..52: W2 chunks; 53: W1; 54..1149: zero acc_g+cnt_g
    transpose_kernel<<<1150, 256, 0, stream>>>(fc_w2, fc_w1, fc_b2, w2t, w1t, b2s, acc_g);
    tpconv_main<<<1024, 512, 0, stream>>>(node_attr, edge_index, edge_attr, edge_sh,
                                          w1t, fc_b1, w2t, b2s, acc_g, cnt_g);
    finalize_kernel<<<(N_NODES * FEAT + 255) / 256, 256, 0, stream>>>(acc_g, cnt_g, node_attr, out);
}

// Round 10
// 166.069 us; speedup vs baseline: 1.0509x; 1.0509x over previous
//
#include <hip/hip_runtime.h>

#define N_NODES 8192
#define N_EDGES 65536
#define FEAT    136
#define WNUM    3392

typedef __attribute__((ext_vector_type(4))) short s16x4;
typedef __attribute__((ext_vector_type(8))) short s16x8;
typedef __attribute__((ext_vector_type(4))) float f32x4;
typedef __attribute__((ext_vector_type(2))) float f32x2;
typedef __attribute__((ext_vector_type(2))) unsigned int u32x2;

__device__ __forceinline__ float b2f(unsigned short h) {
    union { unsigned int u; float f; } v; v.u = ((unsigned int)h) << 16; return v.f;
}
__device__ __forceinline__ unsigned short f2b(float f) {
    union { float f; unsigned int u; } v; v.f = f;
    unsigned int u = v.u;
    unsigned int r = (u + 0x7FFFu + ((u >> 16) & 1u)) >> 16;
    return (unsigned short)r;
}

// extract bf16 #i (compile-time) from packed u32 array -> f32, 1 VALU op
#define BFX(arr, i) __extract_bf16(arr[(i) >> 1], (i) & 1)
__device__ __forceinline__ float __extract_bf16(unsigned int u, int odd) {
    union { unsigned int x; float f; } v;
    v.x = odd ? (u & 0xffff0000u) : (u << 16);
    return v.f;
}

// total scale for W2 column `col` = 1/sqrt(fan_in) * per-i sub-factor (inv_s3/inv_s2)
__device__ __forceinline__ float wscale(int col) {
    const float inv_s3 = 0.57735026918962576f;
    const float inv_s2 = 0.70710678118654752f;
    if (col < 1536) { int i = col >> 5;          return 0.14433756729740643f * (i < 32 ? 1.f : inv_s3); }
    if (col < 2560) { int i = (col - 1536) >> 4; return 0.125f               * (i >= 48 ? inv_s2 : 1.f); }
    if (col < 3200) { int i = (col - 2560) >> 4; return 0.15811388300841897f * (i < 16 ? inv_s2 : 1.f); }
    {               int i = (col - 3200) >> 3;   return 0.20412414523193150f * (i < 16 ? inv_s3 : 1.f); }
}

// ---- prep: W2 -> w2t in 16x16-MFMA fragment order; W1 -> w1t; b2 -> b2s; blocks >=54 zero acc/cnt ----
// w2t layout (shorts): [chunk c (64 cols)][t 0..3][half 0..1][lane 0..63][j 0..7]
//   element = W2scaled[k = half*32 + (lane>>4)*8 + j][col = c*64 + t*16 + (lane&15)]
__global__ void transpose_kernel(const float* __restrict__ w2,
                                 const float* __restrict__ w1,
                                 const float* __restrict__ bias2,
                                 unsigned short* __restrict__ w2t,
                                 unsigned short* __restrict__ w1t,
                                 float* __restrict__ b2s,
                                 float* __restrict__ zero_base) {
    __shared__ float tl[64 * 65];
    const int b = blockIdx.x, tid = threadIdx.x;
    if (b >= 54) {
        // zero acc_g + cnt_g: 4489216 bytes = 280576 float4
        int idx = (b - 54) * 256 + tid;
        float4 z = {0.f, 0.f, 0.f, 0.f};
        if (idx < 280576) ((float4*)zero_base)[idx] = z;
        return;
    }
    if (b < 53) {
        const int c0 = b * 64;
        for (int idx = tid; idx < 4096; idx += 256) {
            int k = idx >> 6, c = idx & 63;
            tl[c * 65 + k] = w2[k * WNUM + c0 + c];          // coalesced read over c
        }
        __syncthreads();
        for (int idx = tid; idx < 4096; idx += 256) {
            int fl   = idx >> 10;            // t
            int rem  = idx & 1023;
            int half = rem >> 9;
            int ln   = (rem >> 3) & 63;
            int j    = idx & 7;
            int q = ln >> 4, nn = ln & 15;
            int cl  = fl * 16 + nn;
            int k   = half * 32 + q * 8 + j;
            int col = c0 + cl;
            w2t[(size_t)b * 4096 + idx] = f2b(tl[cl * 65 + k] * wscale(col));
        }
        if (tid < 64) {
            int col = c0 + tid;
            b2s[col] = bias2[col] * wscale(col);
        }
    } else {
        for (int idx = tid; idx < 4096; idx += 256) {
            int k = idx >> 6, j = idx & 63;
            tl[j * 65 + k] = w1[k * 64 + j];
        }
        __syncthreads();
        for (int idx = tid; idx < 4096; idx += 256) {
            int j = idx >> 6, k = idx & 63;
            w1t[j * 64 + k] = f2b(tl[j * 65 + k]);
        }
    }
}

// async 16B/lane global -> LDS copy; LDS dest is wave-uniform base + lane*16
__device__ __forceinline__ void gload_lds16(const unsigned short* g, unsigned short* l) {
    __builtin_amdgcn_global_load_lds(
        (const __attribute__((address_space(1))) unsigned int*)g,
        (__attribute__((address_space(3))) unsigned int*)l, 16, 0, 0);
}

// ---------------- fused main kernel: 64 edges per block (r7 base + reg-resident x slices) ----------------
// r10 change vs r7: the ~340 per-lane scalar ds_read_u16 x-reads in the K-loop (≈600 cy/interval
// of LDS-pipe + per-chunk latency chains) are replaced by per-section b64 register preloads +
// compile-time bf16 extracts (1 VALU op each). Sections are fully unrolled so every x index is a
// compile-time constant (rule: no runtime-indexed register arrays). 0o sections (3 chunks, index
// depends on quad>>1) keep the LDS path. Everything else identical to the 87 µs r7 baseline.
__global__ __launch_bounds__(256, 4)
void tpconv_main(const float* __restrict__ node_attr,
                 const int* __restrict__ edge_index,
                 const float* __restrict__ edge_attr,
                 const float* __restrict__ edge_sh,
                 const unsigned short* __restrict__ w1t,
                 const float* __restrict__ b1,
                 const unsigned short* __restrict__ w2t,
                 const float* __restrict__ b2s,
                 float* __restrict__ acc_g,
                 float* __restrict__ cnt_g) {
    // LDS layout (37632 B -> 4 blocks/CU):
    //  [0, 18944)      x gather, bf16, 64 rows x stride 148          (live through K-loop)
    //  [18944, 35328)  W2 chunk double-buffer, 2 x 8192 B, fragment-linear
    //     overlays (dead before staging starts):
    //     [18944, 28160)  h tile, bf16, 64 x 72
    //     [28160, 29184)  sh, f32, 64 x 4
    //     [29184, 29440)  dst (int 64)
    //  [37120, 37376)  src (int 64)  -- survives epilogue stage reuse
    //  epilogue: [0, 37120) reused as f32 Y staging, 64 rows x stride 145
    __shared__ __align__(16) char smem[37632];
    unsigned short* x_lds = (unsigned short*)smem;
    unsigned short* wbuf  = (unsigned short*)(smem + 18944);
    unsigned short* h_lds = (unsigned short*)(smem + 18944);
    float* sh_lds = (float*)(smem + 28160);
    int* dst_lds  = (int*)(smem + 29184);
    int* src_lds  = (int*)(smem + 37120);

    const int tid  = threadIdx.x;
    const int lane = tid & 63;
    const int wv   = tid >> 6;       // wave 0..3 -> 16-edge stripe
    const int n    = lane & 15;
    const int quad = lane >> 4;
    const int eb   = blockIdx.x * 64;

    // ---- phase A: indices, sh, counts + h = relu(ea @ W1 + b1) -> h_lds ----
    if (tid < 64) {
        int s = edge_index[eb + tid];
        int d = edge_index[N_EDGES + eb + tid];
        src_lds[tid] = s;
        dst_lds[tid] = d;
        atomicAdd(&cnt_g[s], 1.0f);
        const float4 shv = *(const float4*)&edge_sh[(size_t)(eb + tid) * 4];
        sh_lds[tid * 4 + 0] = shv.x;
        sh_lds[tid * 4 + 1] = shv.y;
        sh_lds[tid * 4 + 2] = shv.z;
        sh_lds[tid * 4 + 3] = shv.w;
    }
    {
        const float* ea = edge_attr + (size_t)(eb + wv * 16 + n) * 64 + quad * 8;
        s16x8 a0, a1;
#pragma unroll
        for (int j = 0; j < 8; ++j) {
            a0[j] = (short)f2b(ea[j]);        // A[m=n][k=quad*8+j]
            a1[j] = (short)f2b(ea[32 + j]);
        }
        for (int ct = 0; ct < 4; ++ct) {
            int col = ct * 16 + n;
            const unsigned short* wp = w1t + col * 64;
            s16x8 bu0 = *(const s16x8*)&wp[quad * 8];
            s16x8 bu1 = *(const s16x8*)&wp[32 + quad * 8];
            f32x4 acc = {0.f, 0.f, 0.f, 0.f};
            acc = __builtin_amdgcn_mfma_f32_16x16x32_bf16(a0, bu0, acc, 0, 0, 0);
            acc = __builtin_amdgcn_mfma_f32_16x16x32_bf16(a1, bu1, acc, 0, 0, 0);
            float bias = b1[col];
            for (int r = 0; r < 4; ++r) {
                float hv = acc[r] + bias;
                hv = hv > 0.f ? hv : 0.f;
                h_lds[(wv * 16 + quad * 4 + r) * 72 + col] = f2b(hv);
            }
        }
    }
    __syncthreads();   // h, dst, sh visible

    // ---- phase B: x gather (node_attr[dst] -> bf16) + pull h/sh into regs ----
    for (int idx = tid; idx < 64 * 34; idx += 256) {
        int e = idx / 34, seg = idx - e * 34;
        const float4 v = *(const float4*)(node_attr + (size_t)dst_lds[e] * FEAT + seg * 4);
        s16x4 pk;
        pk[0] = (short)f2b(v.x); pk[1] = (short)f2b(v.y);
        pk[2] = (short)f2b(v.z); pk[3] = (short)f2b(v.w);
        *(s16x4*)&x_lds[e * 148 + seg * 4] = pk;
    }
    const int eLoc = wv * 16 + n;
    const float sh0 = sh_lds[eLoc * 4 + 0];
    const float s1x = sh_lds[eLoc * 4 + 1];
    const float s1y = sh_lds[eLoc * 4 + 2];
    const float s1z = sh_lds[eLoc * 4 + 3];
    const unsigned short* hp = &h_lds[eLoc * 72];
    s16x8 h0 = *(const s16x8*)&hp[quad * 8];          // B[k=quad*8+j][n=edge]
    s16x8 h1 = *(const s16x8*)&hp[32 + quad * 8];
    const unsigned short* xr = &x_lds[eLoc * 148];

    __syncthreads();   // x visible; h/sh/dst now dead -> wbuf may overwrite

    // prologue: stage chunk 0 + load bias(0); both drained by first in-loop barrier
    {
        const unsigned short* g = w2t + (wv << 10) + (lane << 3);
        unsigned short* l = wbuf + (wv << 10);
        gload_lds16(g, l);
        gload_lds16(g + 512, l + 512);
    }
    f32x4 bvv[4];                       // bias for the CURRENT chunk, pipelined one chunk ahead
#pragma unroll
    for (int t = 0; t < 4; ++t)
        bvv[t] = *(const f32x4*)(b2s + 16 * t + quad * 4);

    f32x2 Y0e2[2][2] = {};   // [row-pair][kk]
    f32x2 Y1o2[2][3] = {};   // [row-pair][comp]
    f32x2 Y1e2[2][3] = {};
    f32x2 Y0o2[2]    = {};

#define CHUNK_TOP(c)                                                          \
    __syncthreads();                                                          \
    if ((c) < 52) {                                                           \
        const unsigned short* g = w2t + (((size_t)(c) + 1) << 12) + (wv << 10) + (lane << 3); \
        unsigned short* l = wbuf + ((((c) + 1) & 1) << 12) + (wv << 10);      \
        gload_lds16(g, l);                                                    \
        gload_lds16(g + 512, l + 512);                                        \
    }                                                                         \
    const unsigned short* cb = wbuf + (((c) & 1) << 12) + (lane << 3);        \
    s16x8 Afr[8];                                                             \
    _Pragma("unroll")                                                         \
    for (int tt = 0; tt < 4; ++tt) {                                          \
        Afr[2 * tt]     = *(const s16x8*)(cb + tt * 1024);                    \
        Afr[2 * tt + 1] = *(const s16x8*)(cb + tt * 1024 + 512);              \
    }

#define CHUNK_REFILL(c)                                                       \
    if ((c) < 52) {                                                           \
        _Pragma("unroll")                                                     \
        for (int t = 0; t < 4; ++t)                                           \
            bvv[t] = *(const f32x4*)(b2s + ((c) + 1) * 64 + 16 * t + quad * 4); \
    }

#define MFMA_T(t)                                                             \
    f32x4 acc = bvv[t];                                                       \
    acc = __builtin_amdgcn_mfma_f32_16x16x32_bf16(Afr[2 * (t)], h0, acc, 0, 0, 0);     \
    acc = __builtin_amdgcn_mfma_f32_16x16x32_bf16(Afr[2 * (t) + 1], h1, acc, 0, 0, 0); \
    f32x2 a01 = {acc[0], acc[1]}; f32x2 a23 = {acc[2], acc[3]};

#define ACC3(Y)                                                               \
    Y[0][0] += a01 * o0; Y[1][0] += a23 * o0;                                 \
    Y[0][1] += a01 * o1; Y[1][1] += a23 * o1;                                 \
    Y[0][2] += a01 * o2; Y[1][2] += a23 * o2;

// per-section x-slice preloads (b64, 8B-aligned: row base 296B, offsets 8p bytes)
#define LOAD_SLICE(ARR, NP, BASE)                                             \
    _Pragma("unroll")                                                         \
    for (int p = 0; p < (NP); ++p) {                                          \
        u32x2 v = *(const u32x2*)(xr + (BASE) + 4 * p);                       \
        ARR[2 * p] = v.x; ARR[2 * p + 1] = v.y;                               \
    }

    // ---- 0e, i < 32 (i = 2c + (t>>1)): x0e[i]*sh0 ----
    {
        unsigned int X0[16];
        LOAD_SLICE(X0, 8, 0)
#pragma unroll
        for (int c = 0; c < 16; ++c) {
            CHUNK_TOP(c)
            float ov = 0.f;
#pragma unroll
            for (int t = 0; t < 4; ++t) {
                MFMA_T(t)
                if ((t & 1) == 0) ov = BFX(X0, 2 * c + (t >> 1)) * sh0;
                const int kk = t & 1;
                Y0e2[0][kk] += a01 * ov;
                Y0e2[1][kk] += a23 * ov;
            }
            CHUNK_REFILL(c)
        }
    }
    // ---- 0e, 32 <= i < 48: dot(x1o[i-32], sh1) ----
    {
        unsigned int X1[24];
        LOAD_SLICE(X1, 12, 32)
#pragma unroll
        for (int c = 16; c < 24; ++c) {
            CHUNK_TOP(c)
            float ov = 0.f;
#pragma unroll
            for (int t = 0; t < 4; ++t) {
                MFMA_T(t)
                if ((t & 1) == 0) {
                    const int j = 3 * (2 * c + (t >> 1) - 32);
                    ov = BFX(X1, j) * s1x + BFX(X1, j + 1) * s1y + BFX(X1, j + 2) * s1z;
                }
                const int kk = t & 1;
                Y0e2[0][kk] += a01 * ov;
                Y0e2[1][kk] += a23 * ov;
            }
            CHUNK_REFILL(c)
        }
    }
    // ---- 1o, i < 32 (i = 4(c-24)+t): x0e[i]*sh1 ----
    {
        unsigned int X0[16];
        LOAD_SLICE(X0, 8, 0)
#pragma unroll
        for (int c = 24; c < 32; ++c) {
            CHUNK_TOP(c)
#pragma unroll
            for (int t = 0; t < 4; ++t) {
                MFMA_T(t)
                float xv = BFX(X0, 4 * (c - 24) + t);
                float o0 = xv * s1x, o1 = xv * s1y, o2 = xv * s1z;
                ACC3(Y1o2)
            }
            CHUNK_REFILL(c)
        }
    }
    // ---- 1o, 32 <= i < 48: x1o[i-32]*sh0 ----
    {
        unsigned int X1[24];
        LOAD_SLICE(X1, 12, 32)
#pragma unroll
        for (int c = 32; c < 36; ++c) {
            CHUNK_TOP(c)
#pragma unroll
            for (int t = 0; t < 4; ++t) {
                MFMA_T(t)
                const int j = 3 * (4 * (c - 24) + t - 32);
                float o0 = BFX(X1, j) * sh0, o1 = BFX(X1, j + 1) * sh0, o2 = BFX(X1, j + 2) * sh0;
                ACC3(Y1o2)
            }
            CHUNK_REFILL(c)
        }
    }
    // ---- 1o, i >= 48: cross(x1e[i-48], sh1) ----
    {
        unsigned int X2[24];
        LOAD_SLICE(X2, 12, 80)
#pragma unroll
        for (int c = 36; c < 40; ++c) {
            CHUNK_TOP(c)
#pragma unroll
            for (int t = 0; t < 4; ++t) {
                MFMA_T(t)
                const int j = 3 * (4 * (c - 24) + t - 48);
                float a0v = BFX(X2, j), a1v = BFX(X2, j + 1), a2v = BFX(X2, j + 2);
                float o0 = a1v * s1z - a2v * s1y;
                float o1 = a2v * s1x - a0v * s1z;
                float o2 = a0v * s1y - a1v * s1x;
                ACC3(Y1o2)
            }
            CHUNK_REFILL(c)
        }
    }
    // ---- 1e, i < 16: cross(x1o[i], sh1) ----
    {
        unsigned int X1[24];
        LOAD_SLICE(X1, 12, 32)
#pragma unroll
        for (int c = 40; c < 44; ++c) {
            CHUNK_TOP(c)
#pragma unroll
            for (int t = 0; t < 4; ++t) {
                MFMA_T(t)
                const int j = 3 * (4 * (c - 40) + t);
                float a0v = BFX(X1, j), a1v = BFX(X1, j + 1), a2v = BFX(X1, j + 2);
                float o0 = a1v * s1z - a2v * s1y;
                float o1 = a2v * s1x - a0v * s1z;
                float o2 = a0v * s1y - a1v * s1x;
                ACC3(Y1e2)
            }
            CHUNK_REFILL(c)
        }
    }
    // ---- 1e, 16 <= i < 32: x1e[i-16]*sh0 ----
    {
        unsigned int X2[24];
        LOAD_SLICE(X2, 12, 80)
#pragma unroll
        for (int c = 44; c < 48; ++c) {
            CHUNK_TOP(c)
#pragma unroll
            for (int t = 0; t < 4; ++t) {
                MFMA_T(t)
                const int j = 3 * (4 * (c - 40) + t - 16);
                float o0 = BFX(X2, j) * sh0, o1 = BFX(X2, j + 1) * sh0, o2 = BFX(X2, j + 2) * sh0;
                ACC3(Y1e2)
            }
            CHUNK_REFILL(c)
        }
    }
    // ---- 1e, i >= 32: x0o[i-32]*sh1 ----
    {
        unsigned int X3[4];
        LOAD_SLICE(X3, 2, 128)
#pragma unroll
        for (int c = 48; c < 50; ++c) {
            CHUNK_TOP(c)
#pragma unroll
            for (int t = 0; t < 4; ++t) {
                MFMA_T(t)
                float xv = BFX(X3, 4 * (c - 40) + t - 32);
                float o0 = xv * s1x, o1 = xv * s1y, o2 = xv * s1z;
                ACC3(Y1e2)
            }
            CHUNK_REFILL(c)
        }
    }
    // ---- 0o, i < 16 (index depends on quad>>1 -> keep LDS path) ----
#pragma unroll
    for (int c = 50; c < 52; ++c) {
        CHUNK_TOP(c)
#pragma unroll
        for (int t = 0; t < 4; ++t) {
            MFMA_T(t)
            int ib = 80 + 3 * (8 * (c - 50) + 2 * t + (quad >> 1));
            float ov = b2f(xr[ib]) * s1x + b2f(xr[ib + 1]) * s1y + b2f(xr[ib + 2]) * s1z;
            Y0o2[0] += a01 * ov;
            Y0o2[1] += a23 * ov;
        }
        CHUNK_REFILL(c)
    }
    // ---- 0o, i >= 16: x0o[i-16]*sh0 ----
    {
        CHUNK_TOP(52)
#pragma unroll
        for (int t = 0; t < 4; ++t) {
            MFMA_T(t)
            float ov = b2f(xr[128 + 2 * t + (quad >> 1)]) * sh0;
            Y0o2[0] += a01 * ov;
            Y0o2[1] += a23 * ov;
        }
    }
#undef ACC3
#undef MFMA_T
#undef CHUNK_TOP
#undef CHUNK_REFILL
#undef LOAD_SLICE

    // ---- stage Y rows in LDS (reuse x+wbuf region, stride 145), then coalesced atomics ----
    __syncthreads();                          // everyone done reading x / wbuf
    float* stage = (float*)smem;              // 64 rows x 145 f32
    {
        float* srow = stage + eLoc * 145;
#pragma unroll
        for (int r = 0; r < 4; ++r) {
            const int p = r >> 1, s = r & 1;
            int qr = quad * 4 + r;
            srow[qr]              = Y0e2[p][0][s];
            srow[16 + qr]         = Y0e2[p][1][s];
            srow[32 + qr * 3 + 0] = Y1o2[p][0][s];
            srow[32 + qr * 3 + 1] = Y1o2[p][1][s];
            srow[32 + qr * 3 + 2] = Y1o2[p][2][s];
            srow[80 + qr * 3 + 0] = Y1e2[p][0][s];
            srow[80 + qr * 3 + 1] = Y1e2[p][1][s];
            srow[80 + qr * 3 + 2] = Y1e2[p][2][s];
            srow[128 + (quad & 1) * 4 + r + (quad >> 1) * 8] = Y0o2[p][s];
        }
    }
    __syncthreads();
    // wave wv scatters its own 16 edges, lanes cover consecutive features (coalesced)
    for (int j = 0; j < 16; ++j) {
        int e = wv * 16 + j;
        float* dp = acc_g + (size_t)src_lds[e] * FEAT;
        const float* sr = stage + e * 145;
        atomicAdd(dp + lane,      sr[lane]);
        atomicAdd(dp + 64 + lane, sr[64 + lane]);
        if (lane < 8)
            atomicAdd(dp + 128 + lane, sr[128 + lane] + sr[136 + lane]);
    }
}

// ---------------- finalize: mean + residual (fp32 out) ----------------
__global__ void finalize_kernel(const float* __restrict__ acc_g,
                                const float* __restrict__ cnt_g,
                                const float* __restrict__ node_attr,
                                float* __restrict__ out) {
    int idx = blockIdx.x * 256 + threadIdx.x;
    if (idx >= N_NODES * FEAT) return;
    int nn = idx / FEAT;
    float c = cnt_g[nn];
    out[idx] = acc_g[idx] / fmaxf(c, 1.0f) + node_attr[idx];
}

extern "C" void kernel_launch(void* const* d_in, const int* in_sizes, int n_in,
                              void* d_out, int out_size, void* d_ws, size_t ws_size,
                              hipStream_t stream) {
    const float* node_attr  = (const float*)d_in[0];
    const int*   edge_index = (const int*)d_in[1];
    const float* edge_attr  = (const float*)d_in[2];
    const float* edge_sh    = (const float*)d_in[3];
    const float* fc_w1      = (const float*)d_in[4];
    const float* fc_b1      = (const float*)d_in[5];
    const float* fc_w2      = (const float*)d_in[6];
    const float* fc_b2      = (const float*)d_in[7];
    float* out = (float*)d_out;

    char* ws = (char*)d_ws;
    float* acc_g = (float*)ws;                                      // 8192*136*4 = 4456448
    float* cnt_g = (float*)(ws + 4456448);                          // 32768
    unsigned short* w2t = (unsigned short*)(ws + 4489216);          // 434176
    unsigned short* w1t = (unsigned short*)(ws + 4489216 + 434176); // 8192
    float* b2s = (float*)(ws + 4489216 + 434176 + 8192);            // 13568

    // blocks 0..52: W2 chunks; 53: W1; 54..1149: zero acc_g+cnt_g
    transpose_kernel<<<1150, 256, 0, stream>>>(fc_w2, fc_w1, fc_b2, w2t, w1t, b2s, acc_g);
    tpconv_main<<<1024, 256, 0, stream>>>(node_attr, edge_index, edge_attr, edge_sh,
                                          w1t, fc_b1, w2t, b2s, acc_g, cnt_g);
    finalize_kernel<<<(N_NODES * FEAT + 255) / 256, 256, 0, stream>>>(acc_g, cnt_g, node_attr, out);
}